// Round 4
// baseline (1213.274 us; speedup 1.0000x reference)
//
#include <hip/hip_runtime.h>
#include <hip/hip_bf16.h>
#include <hip/hip_fp16.h>
#include <stdint.h>

// N=1024 queries, R=100000 refs, H=512, O=256, K=1000.
#define NQ 1024
#define NR 100000
#define KPAD 100352          // 32 k-chunks x 3136 (= 49*64) for GEMM2
#define NH 512
#define NO 256
#define NK 1000
#define NBINS 4096           // sim in [-1,1): bin width 4.883e-4
#define CND_CAP 768
#define DELTA 2.0e-3f        // covers bf16-GEMM sim error + fp16 store quant

typedef __attribute__((ext_vector_type(8))) short bf16x8;
typedef __attribute__((ext_vector_type(8))) _Float16 f16x8;
typedef __attribute__((ext_vector_type(4))) float f32x4;
typedef __attribute__((address_space(3))) void lds_void;
typedef const __attribute__((address_space(1))) void glb_void;

// pack two fp32 into two bf16 (truncation) with one v_perm_b32
static __device__ inline uint32_t pack_bf16_trunc(float lo, float hi) {
    return __builtin_amdgcn_perm(__float_as_uint(hi), __float_as_uint(lo), 0x07060302u);
}

// ---------------------------------------------------------------------------
// K0: fp32 -> bf16 conversion + fp64 inverse L2 norm. One wave per row.
// ---------------------------------------------------------------------------
__global__ __launch_bounds__(256) void conv_norm_kernel(const float* __restrict__ src,
                                                        int rows,
                                                        ushort* __restrict__ dst_bf,
                                                        double* __restrict__ inv_out)
{
    const int wave = threadIdx.x >> 6;
    const int lane = threadIdx.x & 63;
    const int row  = blockIdx.x * 4 + wave;
    if (row >= rows) return;
    const float* p = src + (size_t)row * NH + lane * 8;
    float4 v0 = *(const float4*)p;
    float4 v1 = *(const float4*)(p + 4);
    double s = (double)v0.x * v0.x + (double)v0.y * v0.y
             + (double)v0.z * v0.z + (double)v0.w * v0.w
             + (double)v1.x * v1.x + (double)v1.y * v1.y
             + (double)v1.z * v1.z + (double)v1.w * v1.w;
    uint4 pk;
    pk.x = pack_bf16_trunc(v0.x, v0.y);
    pk.y = pack_bf16_trunc(v0.z, v0.w);
    pk.z = pack_bf16_trunc(v1.x, v1.y);
    pk.w = pack_bf16_trunc(v1.z, v1.w);
    *(uint4*)(dst_bf + (size_t)row * NH + lane * 8) = pk;
    #pragma unroll
    for (int off = 32; off > 0; off >>= 1) s += __shfl_down(s, off, 64);
    if (lane == 0) inv_out[row] = 1.0 / sqrt(s);
}

// ---------------------------------------------------------------------------
// K1: ref_y fp32 [NR][256] -> fp16 TRANSPOSED ryT [256][KPAD] (B of GEMM2).
// 128-row tiles through LDS; tail rows (>= NR) zero-filled.
// ---------------------------------------------------------------------------
__global__ __launch_bounds__(256) void conv_ryt_kernel(const float* __restrict__ ry,
                                                       __half* __restrict__ ryT)
{
    __shared__ __half T[256][136];   // [col][row], pad 136: scattered b16 stores land 2-way (free)
    const int r0 = blockIdx.x * 128;
    #pragma unroll 4
    for (int it = 0; it < 32; ++it) {
        int slot = threadIdx.x + it * 256;      // 8192 float4-slots
        int row  = slot >> 6;
        int c4   = (slot & 63) * 4;
        int rr   = r0 + row;
        float4 v = (rr < NR) ? *(const float4*)(ry + (size_t)rr * NO + c4)
                             : make_float4(0.f, 0.f, 0.f, 0.f);
        T[c4 + 0][row] = __float2half(v.x);
        T[c4 + 1][row] = __float2half(v.y);
        T[c4 + 2][row] = __float2half(v.z);
        T[c4 + 3][row] = __float2half(v.w);
    }
    __syncthreads();
    #pragma unroll 4
    for (int it = 0; it < 16; ++it) {
        int slot = threadIdx.x + it * 256;      // 256 cols x 16 chunks
        int col  = slot >> 4;
        int ch   = (slot & 15) * 8;
        *(uint4*)(ryT + (size_t)col * KPAD + r0 + ch) = *(const uint4*)&T[col][ch];
    }
}

// ---------------------------------------------------------------------------
// K2 (GEMM1): sim = (x . rx^T)*xinv*rinv, bf16 MFMA, fp16 store. (unchanged)
// ---------------------------------------------------------------------------
__global__ __launch_bounds__(256) void gemm_kernel(const ushort* __restrict__ xbf,
                                                   const ushort* __restrict__ rxbf,
                                                   const double* __restrict__ xinv,
                                                   const double* __restrict__ rinv,
                                                   __half* __restrict__ sim)
{
    __shared__ ushort a_lds[128 * 64];
    __shared__ ushort b_lds[128 * 64];
    const int bid = blockIdx.x;
    const int nt  = (bid & 7) + 8 * (bid >> 6);
    const int mt  = (bid >> 3) & 7;
    if (nt >= (NR + 127) / 128) return;
    const int m0 = mt * 128;
    const int r0 = nt * 128;

    const int tid  = threadIdx.x;
    const int lane = tid & 63;
    const int wave = tid >> 6;
    const int wq = (wave >> 1) * 64;
    const int wr = (wave & 1) * 64;

    f32x4 acc[4][4];
    #pragma unroll
    for (int i = 0; i < 4; ++i)
        #pragma unroll
        for (int j = 0; j < 4; ++j)
            #pragma unroll
            for (int r = 0; r < 4; ++r) acc[i][j][r] = 0.0f;

    const int srow  = lane >> 3;
    const int chunk = (lane & 7) ^ (srow & 7);

    for (int kt = 0; kt < NH; kt += 64) {
        #pragma unroll
        for (int ii = 0; ii < 4; ++ii) {
            const int inst = wave * 4 + ii;
            const int row  = inst * 8 + srow;
            const ushort* ga = xbf + (size_t)(m0 + row) * NH + kt + chunk * 8;
            __builtin_amdgcn_global_load_lds((glb_void*)ga,
                (lds_void*)(a_lds + inst * 512), 16, 0, 0);
            int rr = r0 + row; if (rr > NR - 1) rr = NR - 1;
            const ushort* gb = rxbf + (size_t)rr * NH + kt + chunk * 8;
            __builtin_amdgcn_global_load_lds((glb_void*)gb,
                (lds_void*)(b_lds + inst * 512), 16, 0, 0);
        }
        __syncthreads();
        #pragma unroll
        for (int kc = 0; kc < 2; ++kc) {
            const int c  = kc * 4 + (lane >> 4);
            const int px = (c ^ (lane & 7)) * 8;
            bf16x8 af[4], bfr[4];
            #pragma unroll
            for (int i = 0; i < 4; ++i)
                af[i] = *(const bf16x8*)&a_lds[(wq + i * 16 + (lane & 15)) * 64 + px];
            #pragma unroll
            for (int j = 0; j < 4; ++j)
                bfr[j] = *(const bf16x8*)&b_lds[(wr + j * 16 + (lane & 15)) * 64 + px];
            #pragma unroll
            for (int i = 0; i < 4; ++i)
                #pragma unroll
                for (int j = 0; j < 4; ++j)
                    acc[i][j] = __builtin_amdgcn_mfma_f32_16x16x32_bf16(af[i], bfr[j], acc[i][j], 0, 0, 0);
        }
        __syncthreads();
    }

    float xi[4][4];
    #pragma unroll
    for (int i = 0; i < 4; ++i) {
        int mb = m0 + wq + i * 16 + (lane >> 4) * 4;
        #pragma unroll
        for (int r = 0; r < 4; ++r) xi[i][r] = (float)xinv[mb + r];
    }
    #pragma unroll
    for (int j = 0; j < 4; ++j) {
        int nn = r0 + wr + j * 16 + (lane & 15);
        if (nn < NR) {
            float rv = (float)rinv[nn];
            #pragma unroll
            for (int i = 0; i < 4; ++i) {
                int mb = m0 + wq + i * 16 + (lane >> 4) * 4;
                #pragma unroll
                for (int r = 0; r < 4; ++r)
                    sim[(size_t)(mb + r) * NR + nn] = __float2half(acc[i][j][r] * xi[i][r] * rv);
            }
        }
    }
}

// ---------------------------------------------------------------------------
// K3: histogram + thresholds + candidate collect + def-weight sum + row max.
//   definite-in:  s > thi = upper_edge(B*) + DELTA   (provably in top-K)
//   candidate  :  tlo = lower_edge(B*) - DELTA <= s <= thi (fp64 resolve in K4)
// mx[n] = upper edge of highest nonempty bin (>= row max; softmax-invariant).
// ---------------------------------------------------------------------------
__global__ __launch_bounds__(256) void hist_collect_kernel(const __half* __restrict__ sim,
                                                           uint32_t* __restrict__ def_cnt,
                                                           float* __restrict__ def_sum,
                                                           uint32_t* __restrict__ cand_cnt,
                                                           uint32_t* __restrict__ cand_idx,
                                                           float* __restrict__ mx_out,
                                                           float* __restrict__ tlo_out)
{
    __shared__ uint32_t h[NBINS];     // 16 KB
    __shared__ uint32_t ps[256];
    __shared__ float rf[256];
    __shared__ float s_thi, s_tlo, s_mx;
    __shared__ uint32_t s_cc;
    const int n = blockIdx.x, tid = threadIdx.x;
    for (int b = tid; b < NBINS; b += 256) h[b] = 0u;
    __syncthreads();
    const uint4* row8 = (const uint4*)(sim + (size_t)n * NR);
    for (int i8 = tid; i8 < NR / 8; i8 += 256) {
        uint4 v = row8[i8];
        uint32_t wv[4] = {v.x, v.y, v.z, v.w};
        #pragma unroll
        for (int c = 0; c < 4; ++c) {
            float2 f = __half22float2(__builtin_bit_cast(__half2, wv[c]));
            int b0 = (int)((f.x + 1.0f) * 2048.0f); b0 = min(max(b0, 0), NBINS - 1); atomicAdd(&h[b0], 1u);
            int b1 = (int)((f.y + 1.0f) * 2048.0f); b1 = min(max(b1, 0), NBINS - 1); atomicAdd(&h[b1], 1u);
        }
    }
    __syncthreads();
    uint32_t cs = 0;
    #pragma unroll 4
    for (int b = 0; b < 16; ++b) cs += h[tid * 16 + b];
    ps[tid] = cs;
    __syncthreads();
    if (tid == 0) {
        // row max from highest nonempty bin
        int gt = 255;
        while (gt > 0 && ps[gt] == 0u) --gt;
        int bt = gt * 16 + 15;
        while (bt > gt * 16 && h[bt] == 0u) --bt;
        s_mx = (float)(bt + 1) * (1.0f / 2048.0f) - 1.0f;
        // cutoff bin B*
        uint32_t acc = 0; int tc = 0;
        for (int t2 = 255; t2 >= 0; --t2) {
            if (acc + ps[t2] >= (uint32_t)NK) { tc = t2; break; }
            acc += ps[t2];
        }
        int bstar = tc * 16;
        for (int b = tc * 16 + 15; b >= tc * 16; --b) {
            acc += h[b];
            if (acc >= (uint32_t)NK) { bstar = b; break; }
        }
        s_thi = (float)(bstar + 1) * (1.0f / 2048.0f) - 1.0f + DELTA;
        s_tlo = (float)bstar * (1.0f / 2048.0f) - 1.0f - DELTA;
        s_cc = 0u;
    }
    __syncthreads();
    const float thi = s_thi, tlo = s_tlo, mxv = s_mx;
    float dsum = 0.f;
    uint32_t dcnt = 0;
    for (int i8 = tid; i8 < NR / 8; i8 += 256) {
        uint4 v = row8[i8];
        uint32_t wv[4] = {v.x, v.y, v.z, v.w};
        const int base = i8 * 8;
        #pragma unroll
        for (int c = 0; c < 4; ++c) {
            float2 f = __half22float2(__builtin_bit_cast(__half2, wv[c]));
            float sv[2] = {f.x, f.y};
            #pragma unroll
            for (int d = 0; d < 2; ++d) {
                float s = sv[d];
                if (s > thi) {
                    dcnt++;
                    dsum += __expf(s - mxv);
                } else if (s >= tlo) {
                    uint32_t p = atomicAdd(&s_cc, 1u);
                    if (p < CND_CAP) cand_idx[(size_t)n * CND_CAP + p] = (uint32_t)(base + c * 2 + d);
                }
            }
        }
    }
    ps[tid] = dcnt; rf[tid] = dsum;
    __syncthreads();
    for (int off = 128; off > 0; off >>= 1) {
        if (tid < off) { ps[tid] += ps[tid + off]; rf[tid] += rf[tid + off]; }
        __syncthreads();
    }
    if (tid == 0) {
        def_cnt[n]  = ps[0];
        def_sum[n]  = rf[0];
        cand_cnt[n] = s_cc < CND_CAP ? s_cc : CND_CAP;
        mx_out[n]   = mxv;
        tlo_out[n]  = tlo;
    }
}

// ---------------------------------------------------------------------------
// K4: exact fp64 resolution of boundary candidates. Selected -> weight added
// to wsum. Rejected -> simh entry overwritten with -2 so GEMM2's predicate
// (s >= tlo) excludes it. wsum[n] = def_sum + selected candidate weights.
// ---------------------------------------------------------------------------
__global__ __launch_bounds__(256) void resolve_kernel(const float* __restrict__ x,
                                                      const float* __restrict__ rx,
                                                      const double* __restrict__ xinv,
                                                      const double* __restrict__ rinv,
                                                      const uint32_t* __restrict__ def_cnt,
                                                      const float* __restrict__ def_sum,
                                                      const uint32_t* __restrict__ cand_cnt,
                                                      const uint32_t* __restrict__ cand_idx,
                                                      const float* __restrict__ mx_in,
                                                      __half* __restrict__ simh,
                                                      float* __restrict__ wsum)
{
    const int n = blockIdx.x, tid = threadIdx.x;
    const int lane = tid & 63, wave = tid >> 6;
    __shared__ double   cvd[CND_CAP];
    __shared__ uint32_t ci[CND_CAP];
    __shared__ float    red[256];

    const int ca = (int)def_cnt[n];
    int cb = (int)cand_cnt[n]; if (cb > CND_CAP) cb = CND_CAP;
    int t = NK - ca; if (t > cb) t = cb; if (t < 0) t = 0;
    const float mxv = mx_in[n];

    const float* xr = x + (size_t)n * NH;
    for (int j = wave; j < cb; j += 4) {
        uint32_t idx = cand_idx[(size_t)n * CND_CAP + j];
        const float* rr = rx + (size_t)idx * NH;
        double s = 0.0;
        for (int h2 = lane; h2 < NH; h2 += 64)
            s += (double)xr[h2] * (double)rr[h2];
        #pragma unroll
        for (int off = 32; off > 0; off >>= 1) s += __shfl_down(s, off, 64);
        if (lane == 0) { cvd[j] = (s * xinv[n]) * rinv[idx]; ci[j] = idx; }
    }
    __syncthreads();

    // exact rank (val desc, idx asc) matching jax top_k semantics
    float wloc = 0.f;
    for (int j = tid; j < cb; j += 256) {
        double vj = cvd[j]; uint32_t ij = ci[j];
        int rank = 0;
        for (int i = 0; i < cb; ++i) {
            double vi = cvd[i];
            rank += (vi > vj) || (vi == vj && ci[i] < ij);
        }
        float s = __half2float(simh[(size_t)n * NR + ij]);
        if (rank < t) {
            wloc += __expf(s - mxv);
        } else {
            simh[(size_t)n * NR + ij] = __float2half(-2.0f);
        }
    }
    red[tid] = wloc;
    __syncthreads();
    for (int off = 128; off > 0; off >>= 1) {
        if (tid < off) red[tid] += red[tid + off];
        __syncthreads();
    }
    if (tid == 0) wsum[n] = def_sum[n] + red[0];
}

// ---------------------------------------------------------------------------
// K5 (GEMM2): acc += W @ ryT^T where W[m][k] = (simh >= tlo) ? exp(s-mx) : 0,
// computed on the fly in the A-staging path (no dense W materialization).
// f16 MFMA 16x16x32. Block 128m x 128n, 32-way k-split, fp32 atomicAdd.
// Block swizzle: all 16 (m,n) members of one k-chunk share low-3 bid bits ->
// same XCD (perf heuristic): A and B stripes each fetched ~once from HBM.
// ---------------------------------------------------------------------------
__global__ __launch_bounds__(256) void gemm2_kernel(const __half* __restrict__ simh,
                                                    const __half* __restrict__ ryT,
                                                    const float* __restrict__ tlo_in,
                                                    const float* __restrict__ mx_in,
                                                    float* __restrict__ accb)
{
    __shared__ _Float16 a_lds[128 * 64];
    __shared__ _Float16 b_lds[128 * 64];
    __shared__ float s_tlo[128], s_mx[128];

    const int bid = blockIdx.x;                 // 512 blocks
    const int kt  = (bid & 7) + 8 * (bid >> 7); // 0..31 k-chunk
    const int mem = (bid >> 3) & 15;
    const int mt  = mem & 7;
    const int nt  = mem >> 3;
    const int m0  = mt * 128;
    const int n0  = nt * 128;
    const int kb0 = kt * 3136;

    const int tid  = threadIdx.x;
    const int lane = tid & 63;
    const int wave = tid >> 6;
    const int wq = (wave >> 1) * 64;
    const int wr = (wave & 1) * 64;
    const int srow  = lane >> 3;
    const int chunk = (lane & 7) ^ (srow & 7);

    if (tid < 128) { s_tlo[tid] = tlo_in[m0 + tid]; s_mx[tid] = mx_in[m0 + tid]; }

    f32x4 acc[4][4];
    #pragma unroll
    for (int i = 0; i < 4; ++i)
        #pragma unroll
        for (int j = 0; j < 4; ++j)
            #pragma unroll
            for (int r = 0; r < 4; ++r) acc[i][j][r] = 0.0f;
    __syncthreads();

    for (int ks = 0; ks < 49; ++ks) {
        const int k0 = kb0 + ks * 64;
        // stage B: ryT rows n0..n0+127, k-slice 64 (global_load_lds, swizzled)
        #pragma unroll
        for (int ii = 0; ii < 4; ++ii) {
            const int inst = wave * 4 + ii;
            const int row  = inst * 8 + srow;
            const __half* gb = ryT + (size_t)(n0 + row) * KPAD + k0 + chunk * 8;
            __builtin_amdgcn_global_load_lds((glb_void*)gb,
                (lds_void*)(b_lds + inst * 512), 16, 0, 0);
        }
        // stage A: simh tile -> weights (exp transform) -> LDS (swizzled)
        #pragma unroll
        for (int i = 0; i < 4; ++i) {
            int slot = tid + i * 256;           // 128 rows x 8 chunks
            int row  = slot >> 3;
            int c    = slot & 7;
            int kg   = k0 + c * 8;
            const __half* src = simh + (size_t)(m0 + row) * NR + (kg < NR ? kg : 0);
            f16x8 sv = *(const f16x8*)src;
            float tl = s_tlo[row], mv = s_mx[row];
            f16x8 wv;
            #pragma unroll
            for (int j = 0; j < 8; ++j) {
                float s = (float)sv[j];
                float w = (kg + j < NR && s >= tl) ? __expf(s - mv) : 0.f;
                wv[j] = (_Float16)w;
            }
            *(f16x8*)&a_lds[row * 64 + (c ^ (row & 7)) * 8] = wv;
        }
        __syncthreads();
        #pragma unroll
        for (int kc = 0; kc < 2; ++kc) {
            const int c  = kc * 4 + (lane >> 4);
            const int px = (c ^ (lane & 7)) * 8;
            f16x8 af[4], bfr[4];
            #pragma unroll
            for (int i = 0; i < 4; ++i)
                af[i] = *(const f16x8*)&a_lds[(wq + i * 16 + (lane & 15)) * 64 + px];
            #pragma unroll
            for (int j = 0; j < 4; ++j)
                bfr[j] = *(const f16x8*)&b_lds[(wr + j * 16 + (lane & 15)) * 64 + px];
            #pragma unroll
            for (int i = 0; i < 4; ++i)
                #pragma unroll
                for (int j = 0; j < 4; ++j)
                    acc[i][j] = __builtin_amdgcn_mfma_f32_16x16x32_f16(af[i], bfr[j], acc[i][j], 0, 0, 0);
        }
        __syncthreads();
    }

    // epilogue: atomic accumulate partials (C/D: col=lane&15 -> n, row=(lane>>4)*4+r -> m)
    #pragma unroll
    for (int j = 0; j < 4; ++j) {
        int nn = n0 + wr + j * 16 + (lane & 15);
        #pragma unroll
        for (int i = 0; i < 4; ++i) {
            int mb = m0 + wq + i * 16 + (lane >> 4) * 4;
            #pragma unroll
            for (int r = 0; r < 4; ++r)
                atomicAdd(&accb[(size_t)(mb + r) * NO + nn], acc[i][j][r]);
        }
    }
}

// ---------------------------------------------------------------------------
// K6: out = acc / wsum
// ---------------------------------------------------------------------------
__global__ __launch_bounds__(256) void scale_kernel(const float* __restrict__ accb,
                                                    const float* __restrict__ wsum,
                                                    float* __restrict__ out)
{
    const int n = blockIdx.x;
    out[(size_t)n * NO + threadIdx.x] = accb[(size_t)n * NO + threadIdx.x] / wsum[n];
}

// ---------------------------------------------------------------------------
// Workspace layout (bytes), total 364,655,872 (< round-3-proven 371,799,296):
//   simh      0            204,800,000   f16 [1024][100000]
//   rxbf      204,800,000  102,400,000   bf16 [100000][512]
//   ryT       307,200,000   51,380,224   f16 [256][100352]
//   xbf       358,580,224    1,048,576   bf16 [1024][512]
//   rinv      359,628,800      800,000   f64 x 100000
//   xinv      360,428,800        8,192   f64 x 1024
//   mx        360,436,992        4,096   f32 x 1024
//   tlo       360,441,088        4,096   f32 x 1024
//   def_cnt   360,445,184        4,096   u32 x 1024
//   def_sum   360,449,280        4,096   f32 x 1024
//   cand_cnt  360,453,376        4,096   u32 x 1024
//   wsum      360,457,472        4,096   f32 x 1024
//   accb      360,461,568    1,048,576   f32 [1024][256]
//   cand_idx  361,510,144    3,145,728   u32 [1024][768]
// ---------------------------------------------------------------------------
extern "C" void kernel_launch(void* const* d_in, const int* in_sizes, int n_in,
                              void* d_out, int out_size, void* d_ws, size_t ws_size,
                              hipStream_t stream)
{
    const float* x  = (const float*)d_in[0];
    const float* rx = (const float*)d_in[1];
    const float* ry = (const float*)d_in[2];
    float* out = (float*)d_out;

    char* ws = (char*)d_ws;
    __half*   simh     = (__half*)(ws);
    ushort*   rxbf     = (ushort*)(ws + 204800000ull);
    __half*   ryT      = (__half*)(ws + 307200000ull);
    ushort*   xbf      = (ushort*)(ws + 358580224ull);
    double*   rinv     = (double*)(ws + 359628800ull);
    double*   xinv     = (double*)(ws + 360428800ull);
    float*    mxv      = (float*)(ws + 360436992ull);
    float*    tlov     = (float*)(ws + 360441088ull);
    uint32_t* def_cnt  = (uint32_t*)(ws + 360445184ull);
    float*    def_sum  = (float*)(ws + 360449280ull);
    uint32_t* cand_cnt = (uint32_t*)(ws + 360453376ull);
    float*    wsum     = (float*)(ws + 360457472ull);
    float*    accb     = (float*)(ws + 360461568ull);
    uint32_t* cand_idx = (uint32_t*)(ws + 361510144ull);

    hipMemsetAsync(accb, 0, (size_t)NQ * NO * sizeof(float), stream);
    conv_norm_kernel<<<NQ / 4, 256, 0, stream>>>(x, NQ, xbf, xinv);
    conv_norm_kernel<<<NR / 4, 256, 0, stream>>>(rx, NR, rxbf, rinv);
    conv_ryt_kernel<<<KPAD / 128, 256, 0, stream>>>(ry, ryT);
    gemm_kernel<<<6272, 256, 0, stream>>>(xbf, rxbf, xinv, rinv, simh);
    hist_collect_kernel<<<NQ, 256, 0, stream>>>(simh, def_cnt, def_sum, cand_cnt,
                                                cand_idx, mxv, tlov);
    resolve_kernel<<<NQ, 256, 0, stream>>>(x, rx, xinv, rinv, def_cnt, def_sum,
                                           cand_cnt, cand_idx, mxv, simh, wsum);
    gemm2_kernel<<<512, 256, 0, stream>>>(simh, ryT, tlov, mxv, accb);
    scale_kernel<<<NQ, 256, 0, stream>>>(accb, wsum, out);
}